// Round 8
// baseline (781.422 us; speedup 1.0000x reference)
//
#include <hip/hip_runtime.h>
#include <hip/hip_fp16.h>

#define N_NODES 50000
#define N_EDGES 800000
#define DIM 128
#define NODE_TILES 782   // ceil(50000/64)
#define EDGE_TILES 12500 // 800000/64

typedef _Float16 f16;
typedef _Float16 f16x2 __attribute__((ext_vector_type(2)));
typedef _Float16 f16x4 __attribute__((ext_vector_type(4)));
typedef _Float16 f16x8 __attribute__((ext_vector_type(8)));
typedef float    f32x16 __attribute__((ext_vector_type(16)));

__device__ __forceinline__ void sfence() { __builtin_amdgcn_sched_barrier(0); }

// ---------------- shared GEMM pieces ----------------
__device__ __forceinline__ void load_wfrag(const f16* __restrict__ Wh, int ch, int l31, int g,
                                           f16x8 bf[2][8]) {
#pragma unroll
  for (int c = 0; c < 2; ++c)
#pragma unroll
    for (int ks = 0; ks < 8; ++ks)
      bf[c][ks] = *(const f16x8*)(Wh + ((ch * 64 + c * 32 + l31) << 7) + 16 * ks + 8 * g);
}

template <int HALF_OUT, int SILU>
__device__ __forceinline__ void gemm_store(f32x16 acc[2], long M, const float* __restrict__ Bv,
                                           void* __restrict__ OUT,
                                           long tile0, int rc, int ch, int l31, int g) {
#pragma unroll
  for (int c = 0; c < 2; ++c) {
    int col = ch * 64 + c * 32 + l31;
    float bv = Bv[col];
#pragma unroll
    for (int r = 0; r < 16; ++r) {
      long gm = tile0 + rc * 32 + ((r & 3) + 8 * (r >> 2) + 4 * g);
      if (gm < M) {
        float v = acc[c][r] + bv;
        if (SILU) v = v / (1.0f + __expf(-v));
        if (HALF_OUT) ((f16*)OUT)[gm * DIM + col] = (f16)v;
        else          ((float*)OUT)[gm * DIM + col] = v;
      }
    }
  }
}

// ---------------- staging: coalesced, f32->f16, XOR-swizzled LDS ----------------
__device__ __forceinline__ void stage_issue(const float* __restrict__ X, long M, long base,
                                            int tid, float4 sv[8]) {
#pragma unroll
  for (int kk = 0; kk < 8; ++kk) {
    int i = tid + kk * 256;            // [0, 2048): 64 rows x 32 slots of 16B(f32)
    long row = base + (i >> 5);
    long gr = row < M ? row : (M - 1);
    sv[kk] = *(const float4*)(X + gr * DIM + (i & 31) * 4);   // fully coalesced
  }
}

// gather variant: tile rows are elist[base..base+64) (dst-sorted edge order)
__device__ __forceinline__ void stage_issue_g(const float* __restrict__ X,
                                              const int* __restrict__ elist, long base,
                                              int tid, float4 sv[8]) {
#pragma unroll
  for (int kk = 0; kk < 8; ++kk) {
    int i = tid + kk * 256;
    int eid = elist[base + (i >> 5)];      // L2-hot, broadcast within 32-thread group
    sv[kk] = *(const float4*)(X + (long)eid * DIM + (i & 31) * 4);  // full 512B row segs
  }
}

__device__ __forceinline__ void stage_write(const float4 sv[8], int tid, f16* __restrict__ lds) {
#pragma unroll
  for (int kk = 0; kk < 8; ++kk) {
    int i = tid + kk * 256;
    int r = i >> 5, s8 = i & 31;
    f16x4 h;
    h[0] = (f16)sv[kk].x; h[1] = (f16)sv[kk].y; h[2] = (f16)sv[kk].z; h[3] = (f16)sv[kk].w;
    *(f16x4*)(lds + r * 128 + (((s8 >> 1) ^ (r & 15)) << 3) + ((s8 & 1) << 2)) = h;
  }
}

// gemm over LDS tile
__device__ __forceinline__ void mfma_lds_g(const f16* __restrict__ A, int lr, int g,
                                           const f16x8 bf[2][8], f32x16 acc[2]) {
#pragma unroll
  for (int c = 0; c < 2; ++c)
#pragma unroll
    for (int k = 0; k < 16; ++k) acc[c][k] = 0.0f;
#pragma unroll
  for (int ks = 0; ks < 8; ++ks) {
    f16x8 a = *(const f16x8*)(A + lr * 128 + (((2 * ks + g) ^ (lr & 15)) << 3));
    acc[0] = __builtin_amdgcn_mfma_f32_32x32x16_f16(a, bf[0][ks], acc[0], 0, 0, 0);
    acc[1] = __builtin_amdgcn_mfma_f32_32x32x16_f16(a, bf[1][ks], acc[1], 0, 0, 0);
  }
}

// ---------------- GEMM v4 (sequential rows), double-buffered ----------------
template <int HALF_OUT, int SILU>
__global__ __launch_bounds__(256) void gemm_v4(const float* __restrict__ X, long M, int ntiles,
                                               const f16* __restrict__ Wh,
                                               const float* __restrict__ Bv,
                                               void* __restrict__ OUT) {
  __shared__ f16 lbuf[2][64 * 128];
  int tid = threadIdx.x;
  int lane = tid & 63, w = tid >> 6;
  int rc = w >> 1, ch = w & 1, l31 = lane & 31, g = lane >> 5;
  int t0 = blockIdx.x;
  if (t0 >= ntiles) return;
  f16x8 bf[2][8];
  load_wfrag(Wh, ch, l31, g, bf);
  float4 sv[8];
  stage_issue(X, M, (long)t0 * 64, tid, sv);
  stage_write(sv, tid, lbuf[0]);
  __syncthreads();
  int cur = 0;
  int lr = rc * 32 + l31;
  for (int t = t0; t < ntiles; t += gridDim.x) {
    int tn = t + gridDim.x;
    if (tn < ntiles) stage_issue(X, M, (long)tn * 64, tid, sv);
    sfence();
    f32x16 acc[2];
    mfma_lds_g(lbuf[cur], lr, g, bf, acc);
    gemm_store<HALF_OUT, SILU>(acc, M, Bv, OUT, (long)t * 64, rc, ch, l31, g);
    if (tn < ntiles) {
      asm volatile("s_waitcnt vmcnt(0)" ::: "memory");
      stage_write(sv, tid, lbuf[cur ^ 1]);
    }
    __syncthreads();
    cur ^= 1;
  }
}

// ---------------- node4 v4: X-tile staged once, 4 weight mats ----------------
__global__ __launch_bounds__(256) void node4_v4(const float* __restrict__ X,
    const f16* __restrict__ WhAll,
    const float* __restrict__ bq, const float* __restrict__ bk,
    const float* __restrict__ bv_, const float* __restrict__ bs,
    f16* __restrict__ Q, f16* __restrict__ K, f16* __restrict__ V, float* __restrict__ S) {
  __shared__ f16 xs[64 * 128];
  int tid = threadIdx.x;
  int lane = tid & 63, w = tid >> 6;
  int rc = w >> 1, ch = w & 1, l31 = lane & 31, g = lane >> 5;
  int t = blockIdx.x;
  if (t >= NODE_TILES) return;
  long tile0 = (long)t * 64;
  float4 sv[8];
  stage_issue(X, N_NODES, tile0, tid, sv);
  stage_write(sv, tid, xs);
  __syncthreads();
  int lr = rc * 32 + l31;
#pragma unroll 1
  for (int mat = 0; mat < 4; ++mat) {
    f16x8 bf[2][8];
    load_wfrag(WhAll + mat * 16384, ch, l31, g, bf);
    f32x16 acc[2];
    mfma_lds_g(xs, lr, g, bf, acc);
    if (mat == 0)      gemm_store<1, 0>(acc, N_NODES, bq, Q, tile0, rc, ch, l31, g);
    else if (mat == 1) gemm_store<1, 0>(acc, N_NODES, bk, K, tile0, rc, ch, l31, g);
    else if (mat == 2) gemm_store<1, 0>(acc, N_NODES, bv_, V, tile0, rc, ch, l31, g);
    else               gemm_store<0, 0>(acc, N_NODES, bs, S, tile0, rc, ch, l31, g);
  }
}

// ---------------- fused edge-GEMM + attention (emat never hits HBM) ----------------
// Per 64-edge dst-sorted tile: e = ea[elist]@We^T+be via MFMA (stays in regs);
// alpha = q[dst]·(K[src]+e)/4 via 16-lane shfl reduce; w = exp(alpha)*(V[src]+e)
// -> swizzled LDS; segmented sum over dst runs -> atomicAdd into AS/DEN.
__global__ __launch_bounds__(256) void edge_attn(const float* __restrict__ EA,
    const int* __restrict__ elist, const int* __restrict__ srcs, const int* __restrict__ dsts,
    const f16* __restrict__ WeH, const float* __restrict__ be,
    const f16* __restrict__ Qn, const f16* __restrict__ Kn, const f16* __restrict__ Vn,
    float* __restrict__ AS, float* __restrict__ DEN) {
  __shared__ float wbuf[64 * 128];     // 32KB; first 16KB doubles as f16 staging tile
  __shared__ float den_s[64 * 8];
  __shared__ int smeta[128];           // [0..63]=dst, [64..127]=src
  int tid = threadIdx.x;
  int lane = tid & 63, w = tid >> 6;
  int rc = w >> 1, ch = w & 1, l31 = lane & 31, g = lane >> 5;
  long pos0 = (long)blockIdx.x * 64;

  f16* stg = (f16*)wbuf;
  float4 sv[8];
  stage_issue_g(EA, elist, pos0, tid, sv);
  if (tid < 128) smeta[tid] = (tid < 64) ? dsts[pos0 + tid] : srcs[pos0 + tid - 64];
  f16x8 bf[2][8];
  load_wfrag(WeH, ch, l31, g, bf);
  float bcol[2] = { be[ch * 64 + l31], be[ch * 64 + 32 + l31] };
  stage_write(sv, tid, stg);
  __syncthreads();

  int lr = rc * 32 + l31;
  f32x16 acc[2];
  mfma_lds_g(stg, lr, g, bf, acc);
  __syncthreads();                     // all reads of stg done before wbuf overwrite

#pragma unroll
  for (int r = 0; r < 16; ++r) {
    int row = rc * 32 + (r & 3) + 8 * (r >> 2) + 4 * g;
    int d = smeta[row], s = smeta[64 + row];
    const f16* Qp = Qn + (long)d * DIM;
    const f16* Kp = Kn + (long)s * DIM;
    const f16* Vp = Vn + (long)s * DIM;
#pragma unroll
    for (int c = 0; c < 2; ++c) {
      int col = ch * 64 + c * 32 + l31;
      float ev = acc[c][r] + bcol[c];
      float ke = (float)Kp[col] + ev;
      float ve = (float)Vp[col] + ev;
      float p = (float)Qp[col] * ke;
      p += __shfl_xor(p, 1);
      p += __shfl_xor(p, 2);
      p += __shfl_xor(p, 4);
      p += __shfl_xor(p, 8);           // 16-lane group == one head
      float ex = __expf(p * 0.25f);    // /sqrt(16)
      wbuf[row * 128 + (col ^ (row & 31))] = ex * ve;
      if ((l31 & 15) == 0) den_s[row * 8 + (col >> 4)] = ex;
    }
  }
  __syncthreads();

  // segmented reduce over dst-sorted rows; one atomic per (distinct dst, col)
  int col = tid & 127, half = tid >> 7;
  int r0 = half * 32;
  float a = 0.f;
  int dprev = smeta[r0];
  for (int row = r0; row < r0 + 32; ++row) {
    int dcur = smeta[row];
    if (dcur != dprev) {
      atomicAdd(&AS[(long)dprev * DIM + col], a);
      a = 0.f; dprev = dcur;
    }
    a += wbuf[row * 128 + (col ^ (row & 31))];
  }
  atomicAdd(&AS[(long)dprev * DIM + col], a);
  if (tid >= 128 && tid < 136) {
    int h = tid - 128;
    float ds = 0.f;
    int dp = smeta[0];
    for (int row = 0; row < 64; ++row) {
      int dc = smeta[row];
      if (dc != dp) { atomicAdd(&DEN[(long)dp * 8 + h], ds); ds = 0.f; dp = dc; }
      ds += den_s[row * 8 + h];
    }
    atomicAdd(&DEN[(long)dp * 8 + h], ds);
  }
}

// convert all 7 weight matrices f32 -> f16
__global__ void convert7(const float* __restrict__ a0, const float* __restrict__ a1,
                         const float* __restrict__ a2, const float* __restrict__ a3,
                         const float* __restrict__ a4, const float* __restrict__ a5,
                         const float* __restrict__ a6, f16* __restrict__ dst) {
  int i = blockIdx.x * blockDim.x + threadIdx.x;
  int mat = i >> 14, el = i & 16383;
  const float* s = (mat == 0) ? a0 : (mat == 1) ? a1 : (mat == 2) ? a2 : (mat == 3) ? a3
                 : (mat == 4) ? a4 : (mat == 5) ? a5 : a6;
  dst[i] = (f16)s[el];
}

// ---------------- CSR build ----------------
__global__ void hist_k(const int* __restrict__ ei, int* __restrict__ counts) {
  for (long e = blockIdx.x * (long)blockDim.x + threadIdx.x; e < N_EDGES;
       e += (long)gridDim.x * blockDim.x)
    atomicAdd(&counts[ei[N_EDGES + e]], 1);
}

__global__ __launch_bounds__(1024) void scan_k(const int* __restrict__ counts,
                                               int* __restrict__ offs, int* __restrict__ cursor) {
  __shared__ int sd[1024];
  int tid = threadIdx.x;
  const int CH = (N_NODES + 1023) / 1024;
  int i0 = tid * CH;
  int s = 0;
  for (int i = 0; i < CH; ++i) { int idx = i0 + i; if (idx < N_NODES) s += counts[idx]; }
  sd[tid] = s; __syncthreads();
  for (int off = 1; off < 1024; off <<= 1) {
    int v = (tid >= off) ? sd[tid - off] : 0;
    __syncthreads();
    sd[tid] += v;
    __syncthreads();
  }
  int run = sd[tid] - s;
  for (int i = 0; i < CH; ++i) {
    int idx = i0 + i;
    if (idx < N_NODES) { offs[idx] = run; cursor[idx] = run; run += counts[idx]; }
  }
  if (tid == 1023) offs[N_NODES] = run;
}

// scatter: elist[pos]=edge id; srcs/dsts[pos]=src/dst node of that edge
__global__ void scatter_k(const int* __restrict__ ei, int* __restrict__ cursor,
                          int* __restrict__ elist, int* __restrict__ srcs,
                          int* __restrict__ dsts) {
  for (long e = blockIdx.x * (long)blockDim.x + threadIdx.x; e < N_EDGES;
       e += (long)gridDim.x * blockDim.x) {
    int d = ei[N_EDGES + e];
    int pos = atomicAdd(&cursor[d], 1);
    elist[pos] = (int)e;
    srcs[pos] = ei[e];
    dsts[pos] = d;
  }
}

// node1 = base + LN(AS/den + Skip) * g + b   (softmax division folded in)
__global__ __launch_bounds__(256) void post_ln_div(const float* __restrict__ AS,
    const float* __restrict__ DEN, const float* __restrict__ Skip,
    const float* __restrict__ base, const float* __restrict__ g,
    const float* __restrict__ b, float* __restrict__ outp) {
  int n = blockIdx.x * 4 + (threadIdx.x >> 6);
  if (n >= N_NODES) return;
  int lane = threadIdx.x & 63;
  float inv = 1.f / (DEN[(long)n * 8 + (lane >> 3)] + 1e-16f);
  float2 x = *(const float2*)(AS + (long)n * DIM + 2 * lane);
  float2 sk = *(const float2*)(Skip + (long)n * DIM + 2 * lane);
  x.x = x.x * inv + sk.x;
  x.y = x.y * inv + sk.y;
  float sm = x.x + x.y;
  for (int m = 1; m < 64; m <<= 1) sm += __shfl_xor(sm, m);
  float mu = sm * (1.f / 128.f);
  float dx = x.x - mu, dy = x.y - mu;
  float ss = dx * dx + dy * dy;
  for (int m = 1; m < 64; m <<= 1) ss += __shfl_xor(ss, m);
  float r = rsqrtf(ss * (1.f / 128.f) + 1e-5f);
  float2 gg = *(const float2*)(g + 2 * lane);
  float2 bb = *(const float2*)(b + 2 * lane);
  float2 bs = *(const float2*)(base + (long)n * DIM + 2 * lane);
  float2 o;
  o.x = bs.x + dx * r * gg.x + bb.x;
  o.y = bs.y + dy * r * gg.y + bb.y;
  *(float2*)(outp + (long)n * DIM + 2 * lane) = o;
}

// out = base + LN(xa) * g + b
__global__ __launch_bounds__(256) void post_ln(const float* __restrict__ xa,
    const float* __restrict__ base, const float* __restrict__ g,
    const float* __restrict__ b, float* __restrict__ outp) {
  int n = blockIdx.x * 4 + (threadIdx.x >> 6);
  if (n >= N_NODES) return;
  int lane = threadIdx.x & 63;
  float2 x = *(const float2*)(xa + (long)n * DIM + 2 * lane);
  float sm = x.x + x.y;
  for (int m = 1; m < 64; m <<= 1) sm += __shfl_xor(sm, m);
  float mu = sm * (1.f / 128.f);
  float dx = x.x - mu, dy = x.y - mu;
  float ss = dx * dx + dy * dy;
  for (int m = 1; m < 64; m <<= 1) ss += __shfl_xor(ss, m);
  float r = rsqrtf(ss * (1.f / 128.f) + 1e-5f);
  float2 gg = *(const float2*)(g + 2 * lane);
  float2 bb = *(const float2*)(b + 2 * lane);
  float2 bs = *(const float2*)(base + (long)n * DIM + 2 * lane);
  float2 o;
  o.x = bs.x + dx * r * gg.x + bb.x;
  o.y = bs.y + dy * r * gg.y + bb.y;
  *(float2*)(outp + (long)n * DIM + 2 * lane) = o;
}

// ---------------- launch ----------------
extern "C" void kernel_launch(void* const* d_in, const int* in_sizes, int n_in,
                              void* d_out, int out_size, void* d_ws, size_t ws_size,
                              hipStream_t stream) {
  (void)in_sizes; (void)n_in; (void)out_size; (void)ws_size;
  const int*   ei  = (const int*)d_in[0];
  const float* x0  = (const float*)d_in[1];
  const float* ea  = (const float*)d_in[2];
  const float* Wq  = (const float*)d_in[3];  const float* bq = (const float*)d_in[4];
  const float* Wk  = (const float*)d_in[5];  const float* bk = (const float*)d_in[6];
  const float* Wv  = (const float*)d_in[7];  const float* bv = (const float*)d_in[8];
  const float* We  = (const float*)d_in[9];  const float* be = (const float*)d_in[10];
  const float* Wsk = (const float*)d_in[11]; const float* bsk = (const float*)d_in[12];
  const float* W1  = (const float*)d_in[13]; const float* b1 = (const float*)d_in[14];
  const float* W2  = (const float*)d_in[15]; const float* b2 = (const float*)d_in[16];
  const float* g1  = (const float*)d_in[17]; const float* lb1 = (const float*)d_in[18];
  const float* g2  = (const float*)d_in[19]; const float* lb2 = (const float*)d_in[20];

  char* ws = (char*)d_ws;
  f16*   Qn     = (f16*)(ws + 0);              // 12.8M
  f16*   Kn     = (f16*)(ws + 12800000L);      // 12.8M
  f16*   Vn     = (f16*)(ws + 25600000L);      // 12.8M
  float* Skip   = (float*)(ws + 38400000L);    // 25.6M -> 64000000
  int*   offs   = (int*)(ws + 64000000L);      // 200,192
  f16*   WhAll  = (f16*)(ws + 64200192L);      // 229,376 (overlays cursor, dead after CSR)
  int*   cursor = (int*)(ws + 64200192L);
  int*   counts = (int*)(ws + 64429568L);      // 200,000
  int*   elist  = (int*)(ws + 64629760L);      // 3.2M
  int*   srcs   = (int*)(ws + 67829760L);      // 3.2M
  int*   dsts   = (int*)(ws + 71029760L);      // 3.2M
  float* den    = (float*)(ws + 74229760L);    // 1.6M
  float* node1  = (float*)(ws + 75829760L);    // 25.6M -> 101,429,760
  float* hid    = (float*)(ws + 38400000L);    // reuse Skip (dead after post_ln_div)
  float* h2     = (float*)(ws + 0);            // reuse Qn/Kn (dead after edge_attn)
  float* attn   = (float*)d_out;               // atomic accumulation target; overwritten at end

  (void)hipMemsetAsync(counts, 0, N_NODES * sizeof(int), stream);
  (void)hipMemsetAsync(attn, 0, (size_t)N_NODES * DIM * sizeof(float), stream);
  (void)hipMemsetAsync(den, 0, (size_t)N_NODES * 8 * sizeof(float), stream);
  hist_k<<<1024, 256, 0, stream>>>(ei, counts);
  scan_k<<<1, 1024, 0, stream>>>(counts, offs, cursor);
  scatter_k<<<1024, 256, 0, stream>>>(ei, cursor, elist, srcs, dsts);
  convert7<<<112, 1024, 0, stream>>>(Wq, Wk, Wv, Wsk, We, W1, W2, WhAll);

  node4_v4<<<NODE_TILES, 256, 0, stream>>>(x0, WhAll, bq, bk, bv, bsk, Qn, Kn, Vn, Skip);
  edge_attn<<<EDGE_TILES, 256, 0, stream>>>(ea, elist, srcs, dsts, WhAll + 4 * 16384, be,
                                            Qn, Kn, Vn, attn, den);
  post_ln_div<<<12500, 256, 0, stream>>>(attn, den, Skip, x0, g1, lb1, node1);
  gemm_v4<0, 1><<<NODE_TILES, 256, 0, stream>>>(node1, (long)N_NODES, NODE_TILES,
                                                WhAll + 5 * 16384, b1, hid);
  gemm_v4<0, 0><<<NODE_TILES, 256, 0, stream>>>(hid, (long)N_NODES, NODE_TILES,
                                                WhAll + 6 * 16384, b2, h2);
  post_ln<<<12500, 256, 0, stream>>>(h2, node1, g2, lb2, (float*)d_out);
}

// Round 9
// 730.916 us; speedup vs baseline: 1.0691x; 1.0691x over previous
//
#include <hip/hip_runtime.h>
#include <hip/hip_fp16.h>

#define N_NODES 50000
#define N_EDGES 800000
#define DIM 128
#define NODE_TILES 782   // ceil(50000/64)
#define EDGE_TILES 12500 // 800000/64

typedef _Float16 f16;
typedef _Float16 f16x2 __attribute__((ext_vector_type(2)));
typedef _Float16 f16x4 __attribute__((ext_vector_type(4)));
typedef _Float16 f16x8 __attribute__((ext_vector_type(8)));
typedef float    f32x16 __attribute__((ext_vector_type(16)));

__device__ __forceinline__ void sfence() { __builtin_amdgcn_sched_barrier(0); }

// ---------------- shared GEMM pieces ----------------
__device__ __forceinline__ void load_wfrag(const f16* __restrict__ Wh, int ch, int l31, int g,
                                           f16x8 bf[2][8]) {
#pragma unroll
  for (int c = 0; c < 2; ++c)
#pragma unroll
    for (int ks = 0; ks < 8; ++ks)
      bf[c][ks] = *(const f16x8*)(Wh + ((ch * 64 + c * 32 + l31) << 7) + 16 * ks + 8 * g);
}

template <int HALF_OUT, int SILU>
__device__ __forceinline__ void gemm_store(f32x16 acc[2], long M, const float* __restrict__ Bv,
                                           void* __restrict__ OUT,
                                           long tile0, int rc, int ch, int l31, int g) {
#pragma unroll
  for (int c = 0; c < 2; ++c) {
    int col = ch * 64 + c * 32 + l31;
    float bv = Bv[col];
#pragma unroll
    for (int r = 0; r < 16; ++r) {
      long gm = tile0 + rc * 32 + ((r & 3) + 8 * (r >> 2) + 4 * g);
      if (gm < M) {
        float v = acc[c][r] + bv;
        if (SILU) v = v / (1.0f + __expf(-v));
        if (HALF_OUT) ((f16*)OUT)[gm * DIM + col] = (f16)v;
        else          ((float*)OUT)[gm * DIM + col] = v;
      }
    }
  }
}

// ---------------- staging: coalesced, f32->f16, XOR-swizzled LDS ----------------
__device__ __forceinline__ void stage_issue(const float* __restrict__ X, long M, long base,
                                            int tid, float4 sv[8]) {
#pragma unroll
  for (int kk = 0; kk < 8; ++kk) {
    int i = tid + kk * 256;            // [0, 2048): 64 rows x 32 slots of 16B(f32)
    long row = base + (i >> 5);
    long gr = row < M ? row : (M - 1);
    sv[kk] = *(const float4*)(X + gr * DIM + (i & 31) * 4);   // fully coalesced
  }
}

// gather variant: tile rows are elist[base..base+64) (dst-sorted edge order)
__device__ __forceinline__ void stage_issue_g(const float* __restrict__ X,
                                              const int* __restrict__ elist, long base,
                                              int tid, float4 sv[8]) {
#pragma unroll
  for (int kk = 0; kk < 8; ++kk) {
    int i = tid + kk * 256;
    int eid = elist[base + (i >> 5)];      // L2-hot, broadcast within 32-thread group
    sv[kk] = *(const float4*)(X + (long)eid * DIM + (i & 31) * 4);  // full 512B row segs
  }
}

__device__ __forceinline__ void stage_write(const float4 sv[8], int tid, f16* __restrict__ lds) {
#pragma unroll
  for (int kk = 0; kk < 8; ++kk) {
    int i = tid + kk * 256;
    int r = i >> 5, s8 = i & 31;
    f16x4 h;
    h[0] = (f16)sv[kk].x; h[1] = (f16)sv[kk].y; h[2] = (f16)sv[kk].z; h[3] = (f16)sv[kk].w;
    *(f16x4*)(lds + r * 128 + (((s8 >> 1) ^ (r & 15)) << 3) + ((s8 & 1) << 2)) = h;
  }
}

// gemm over LDS tile
__device__ __forceinline__ void mfma_lds_g(const f16* __restrict__ A, int lr, int g,
                                           const f16x8 bf[2][8], f32x16 acc[2]) {
#pragma unroll
  for (int c = 0; c < 2; ++c)
#pragma unroll
    for (int k = 0; k < 16; ++k) acc[c][k] = 0.0f;
#pragma unroll
  for (int ks = 0; ks < 8; ++ks) {
    f16x8 a = *(const f16x8*)(A + lr * 128 + (((2 * ks + g) ^ (lr & 15)) << 3));
    acc[0] = __builtin_amdgcn_mfma_f32_32x32x16_f16(a, bf[0][ks], acc[0], 0, 0, 0);
    acc[1] = __builtin_amdgcn_mfma_f32_32x32x16_f16(a, bf[1][ks], acc[1], 0, 0, 0);
  }
}

// ---------------- GEMM v4 (sequential rows), double-buffered ----------------
template <int HALF_OUT, int SILU>
__global__ __launch_bounds__(256) void gemm_v4(const float* __restrict__ X, long M, int ntiles,
                                               const f16* __restrict__ Wh,
                                               const float* __restrict__ Bv,
                                               void* __restrict__ OUT) {
  __shared__ f16 lbuf[2][64 * 128];
  int tid = threadIdx.x;
  int lane = tid & 63, w = tid >> 6;
  int rc = w >> 1, ch = w & 1, l31 = lane & 31, g = lane >> 5;
  int t0 = blockIdx.x;
  if (t0 >= ntiles) return;
  f16x8 bf[2][8];
  load_wfrag(Wh, ch, l31, g, bf);
  float4 sv[8];
  stage_issue(X, M, (long)t0 * 64, tid, sv);
  stage_write(sv, tid, lbuf[0]);
  __syncthreads();
  int cur = 0;
  int lr = rc * 32 + l31;
  for (int t = t0; t < ntiles; t += gridDim.x) {
    int tn = t + gridDim.x;
    if (tn < ntiles) stage_issue(X, M, (long)tn * 64, tid, sv);
    sfence();
    f32x16 acc[2];
    mfma_lds_g(lbuf[cur], lr, g, bf, acc);
    gemm_store<HALF_OUT, SILU>(acc, M, Bv, OUT, (long)t * 64, rc, ch, l31, g);
    if (tn < ntiles) {
      asm volatile("s_waitcnt vmcnt(0)" ::: "memory");
      stage_write(sv, tid, lbuf[cur ^ 1]);
    }
    __syncthreads();
    cur ^= 1;
  }
}

// ---------------- node4 v4: X-tile staged once, 4 weight mats ----------------
__global__ __launch_bounds__(256) void node4_v4(const float* __restrict__ X,
    const f16* __restrict__ WhAll,
    const float* __restrict__ bq, const float* __restrict__ bk,
    const float* __restrict__ bv_, const float* __restrict__ bs,
    f16* __restrict__ Q, f16* __restrict__ K, f16* __restrict__ V, float* __restrict__ S) {
  __shared__ f16 xs[64 * 128];
  int tid = threadIdx.x;
  int lane = tid & 63, w = tid >> 6;
  int rc = w >> 1, ch = w & 1, l31 = lane & 31, g = lane >> 5;
  int t = blockIdx.x;
  if (t >= NODE_TILES) return;
  long tile0 = (long)t * 64;
  float4 sv[8];
  stage_issue(X, N_NODES, tile0, tid, sv);
  stage_write(sv, tid, xs);
  __syncthreads();
  int lr = rc * 32 + l31;
#pragma unroll 1
  for (int mat = 0; mat < 4; ++mat) {
    f16x8 bf[2][8];
    load_wfrag(WhAll + mat * 16384, ch, l31, g, bf);
    f32x16 acc[2];
    mfma_lds_g(xs, lr, g, bf, acc);
    if (mat == 0)      gemm_store<1, 0>(acc, N_NODES, bq, Q, tile0, rc, ch, l31, g);
    else if (mat == 1) gemm_store<1, 0>(acc, N_NODES, bk, K, tile0, rc, ch, l31, g);
    else if (mat == 2) gemm_store<1, 0>(acc, N_NODES, bv_, V, tile0, rc, ch, l31, g);
    else               gemm_store<0, 0>(acc, N_NODES, bs, S, tile0, rc, ch, l31, g);
  }
}

// ---------------- fused edge-GEMM + attention v2 ----------------
// Per 64-edge dst-sorted tile:
//   stage EA rows (gather) + K[src]/V[src] rows (coalesced f16x8) + dst meta, one cluster;
//   e = EA@We^T + be via MFMA (stays in registers);
//   alpha via 16-lane shfl reduce (K/V read from LDS, Q scalar L1-hot);
//   per-lane run-accumulation over sorted dst; atomicAdd only at run boundaries.
__global__ __launch_bounds__(256) void edge_attn(const float* __restrict__ EA,
    const int* __restrict__ elist, const int* __restrict__ srcs, const int* __restrict__ dsts,
    const f16* __restrict__ WeH, const float* __restrict__ be,
    const f16* __restrict__ Qn, const f16* __restrict__ Kn, const f16* __restrict__ Vn,
    float* __restrict__ AS, float* __restrict__ DEN) {
  __shared__ f16 stg[64 * 128];    // 16 KB  (EA tile, swizzled, for MFMA)
  __shared__ f16 klds[64 * 128];   // 16 KB  (K[src] rows, linear)
  __shared__ f16 vlds[64 * 128];   // 16 KB  (V[src] rows, linear)
  __shared__ int smeta[64];        // dst per row
  int tid = threadIdx.x;
  int lane = tid & 63, w = tid >> 6;
  int rc = w >> 1, ch = w & 1, l31 = lane & 31, g = lane >> 5;
  long pos0 = (long)blockIdx.x * 64;

  // ---- one load cluster: EA gather + K/V gather + meta + W frags ----
  float4 sv[8];
  stage_issue_g(EA, elist, pos0, tid, sv);
  f16x8 kv[4], vv[4];
#pragma unroll
  for (int k = 0; k < 4; ++k) {
    int i = tid + k * 256;                 // 1024 slots: 64 rows x 16 slots of 16B
    int row = i >> 4, slot = i & 15;
    int s = srcs[pos0 + row];
    kv[k] = *(const f16x8*)(Kn + (long)s * DIM + slot * 8);
    vv[k] = *(const f16x8*)(Vn + (long)s * DIM + slot * 8);
  }
  if (tid < 64) smeta[tid] = dsts[pos0 + tid];
  f16x8 bf[2][8];
  load_wfrag(WeH, ch, l31, g, bf);
  float bcol[2] = { be[ch * 64 + l31], be[ch * 64 + 32 + l31] };
  sfence();

  stage_write(sv, tid, stg);
#pragma unroll
  for (int k = 0; k < 4; ++k) {
    int i = tid + k * 256;
    int row = i >> 4, slot = i & 15;
    *(f16x8*)(klds + row * 128 + slot * 8) = kv[k];
    *(f16x8*)(vlds + row * 128 + slot * 8) = vv[k];
  }
  __syncthreads();

  int lr = rc * 32 + l31;
  f32x16 acc[2];
  mfma_lds_g(stg, lr, g, bf, acc);

  // ---- alpha + online weighted sum, run-accumulated over sorted dst ----
  int col0 = ch * 64 + l31, col1 = ch * 64 + 32 + l31;
  bool denlane = (l31 & 15) == 0;
  int h0 = col0 >> 4, h1 = col1 >> 4;
  float as0 = 0.f, as1 = 0.f, dn0 = 0.f, dn1 = 0.f;
  int dprev = smeta[rc * 32 + 4 * g];
#pragma unroll
  for (int r = 0; r < 16; ++r) {
    int row = rc * 32 + (r & 3) + 8 * (r >> 2) + 4 * g;
    int d = smeta[row];
    if (d != dprev) {
      atomicAdd(&AS[(long)dprev * DIM + col0], as0);
      atomicAdd(&AS[(long)dprev * DIM + col1], as1);
      if (denlane) {
        atomicAdd(&DEN[(long)dprev * 8 + h0], dn0);
        atomicAdd(&DEN[(long)dprev * 8 + h1], dn1);
      }
      as0 = as1 = dn0 = dn1 = 0.f;
      dprev = d;
    }
    const f16* Qp = Qn + (long)d * DIM;
    {
      float ev = acc[0][r] + bcol[0];
      float ke = (float)klds[row * 128 + col0] + ev;
      float ve = (float)vlds[row * 128 + col0] + ev;
      float p = (float)Qp[col0] * ke;
      p += __shfl_xor(p, 1); p += __shfl_xor(p, 2);
      p += __shfl_xor(p, 4); p += __shfl_xor(p, 8);
      float ex = __expf(p * 0.25f);
      as0 += ex * ve; dn0 += ex;
    }
    {
      float ev = acc[1][r] + bcol[1];
      float ke = (float)klds[row * 128 + col1] + ev;
      float ve = (float)vlds[row * 128 + col1] + ev;
      float p = (float)Qp[col1] * ke;
      p += __shfl_xor(p, 1); p += __shfl_xor(p, 2);
      p += __shfl_xor(p, 4); p += __shfl_xor(p, 8);
      float ex = __expf(p * 0.25f);
      as1 += ex * ve; dn1 += ex;
    }
  }
  atomicAdd(&AS[(long)dprev * DIM + col0], as0);
  atomicAdd(&AS[(long)dprev * DIM + col1], as1);
  if (denlane) {
    atomicAdd(&DEN[(long)dprev * 8 + h0], dn0);
    atomicAdd(&DEN[(long)dprev * 8 + h1], dn1);
  }
}

// convert all 7 weight matrices f32 -> f16
__global__ void convert7(const float* __restrict__ a0, const float* __restrict__ a1,
                         const float* __restrict__ a2, const float* __restrict__ a3,
                         const float* __restrict__ a4, const float* __restrict__ a5,
                         const float* __restrict__ a6, f16* __restrict__ dst) {
  int i = blockIdx.x * blockDim.x + threadIdx.x;
  int mat = i >> 14, el = i & 16383;
  const float* s = (mat == 0) ? a0 : (mat == 1) ? a1 : (mat == 2) ? a2 : (mat == 3) ? a3
                 : (mat == 4) ? a4 : (mat == 5) ? a5 : a6;
  dst[i] = (f16)s[el];
}

// ---------------- CSR build ----------------
__global__ void hist_k(const int* __restrict__ ei, int* __restrict__ counts) {
  for (long e = blockIdx.x * (long)blockDim.x + threadIdx.x; e < N_EDGES;
       e += (long)gridDim.x * blockDim.x)
    atomicAdd(&counts[ei[N_EDGES + e]], 1);
}

__global__ __launch_bounds__(1024) void scan_k(const int* __restrict__ counts,
                                               int* __restrict__ offs, int* __restrict__ cursor) {
  __shared__ int sd[1024];
  int tid = threadIdx.x;
  const int CH = (N_NODES + 1023) / 1024;
  int i0 = tid * CH;
  int s = 0;
  for (int i = 0; i < CH; ++i) { int idx = i0 + i; if (idx < N_NODES) s += counts[idx]; }
  sd[tid] = s; __syncthreads();
  for (int off = 1; off < 1024; off <<= 1) {
    int v = (tid >= off) ? sd[tid - off] : 0;
    __syncthreads();
    sd[tid] += v;
    __syncthreads();
  }
  int run = sd[tid] - s;
  for (int i = 0; i < CH; ++i) {
    int idx = i0 + i;
    if (idx < N_NODES) { offs[idx] = run; cursor[idx] = run; run += counts[idx]; }
  }
  if (tid == 1023) offs[N_NODES] = run;
}

// scatter: elist[pos]=edge id; srcs/dsts[pos]=src/dst node of that edge
__global__ void scatter_k(const int* __restrict__ ei, int* __restrict__ cursor,
                          int* __restrict__ elist, int* __restrict__ srcs,
                          int* __restrict__ dsts) {
  for (long e = blockIdx.x * (long)blockDim.x + threadIdx.x; e < N_EDGES;
       e += (long)gridDim.x * blockDim.x) {
    int d = ei[N_EDGES + e];
    int pos = atomicAdd(&cursor[d], 1);
    elist[pos] = (int)e;
    srcs[pos] = ei[e];
    dsts[pos] = d;
  }
}

// node1 = base + LN(AS/den + Skip) * g + b   (softmax division folded in)
__global__ __launch_bounds__(256) void post_ln_div(const float* __restrict__ AS,
    const float* __restrict__ DEN, const float* __restrict__ Skip,
    const float* __restrict__ base, const float* __restrict__ g,
    const float* __restrict__ b, float* __restrict__ outp) {
  int n = blockIdx.x * 4 + (threadIdx.x >> 6);
  if (n >= N_NODES) return;
  int lane = threadIdx.x & 63;
  float inv = 1.f / (DEN[(long)n * 8 + (lane >> 3)] + 1e-16f);
  float2 x = *(const float2*)(AS + (long)n * DIM + 2 * lane);
  float2 sk = *(const float2*)(Skip + (long)n * DIM + 2 * lane);
  x.x = x.x * inv + sk.x;
  x.y = x.y * inv + sk.y;
  float sm = x.x + x.y;
  for (int m = 1; m < 64; m <<= 1) sm += __shfl_xor(sm, m);
  float mu = sm * (1.f / 128.f);
  float dx = x.x - mu, dy = x.y - mu;
  float ss = dx * dx + dy * dy;
  for (int m = 1; m < 64; m <<= 1) ss += __shfl_xor(ss, m);
  float r = rsqrtf(ss * (1.f / 128.f) + 1e-5f);
  float2 gg = *(const float2*)(g + 2 * lane);
  float2 bb = *(const float2*)(b + 2 * lane);
  float2 bs = *(const float2*)(base + (long)n * DIM + 2 * lane);
  float2 o;
  o.x = bs.x + dx * r * gg.x + bb.x;
  o.y = bs.y + dy * r * gg.y + bb.y;
  *(float2*)(outp + (long)n * DIM + 2 * lane) = o;
}

// out = base + LN(xa) * g + b
__global__ __launch_bounds__(256) void post_ln(const float* __restrict__ xa,
    const float* __restrict__ base, const float* __restrict__ g,
    const float* __restrict__ b, float* __restrict__ outp) {
  int n = blockIdx.x * 4 + (threadIdx.x >> 6);
  if (n >= N_NODES) return;
  int lane = threadIdx.x & 63;
  float2 x = *(const float2*)(xa + (long)n * DIM + 2 * lane);
  float sm = x.x + x.y;
  for (int m = 1; m < 64; m <<= 1) sm += __shfl_xor(sm, m);
  float mu = sm * (1.f / 128.f);
  float dx = x.x - mu, dy = x.y - mu;
  float ss = dx * dx + dy * dy;
  for (int m = 1; m < 64; m <<= 1) ss += __shfl_xor(ss, m);
  float r = rsqrtf(ss * (1.f / 128.f) + 1e-5f);
  float2 gg = *(const float2*)(g + 2 * lane);
  float2 bb = *(const float2*)(b + 2 * lane);
  float2 bs = *(const float2*)(base + (long)n * DIM + 2 * lane);
  float2 o;
  o.x = bs.x + dx * r * gg.x + bb.x;
  o.y = bs.y + dy * r * gg.y + bb.y;
  *(float2*)(outp + (long)n * DIM + 2 * lane) = o;
}

// ---------------- launch ----------------
extern "C" void kernel_launch(void* const* d_in, const int* in_sizes, int n_in,
                              void* d_out, int out_size, void* d_ws, size_t ws_size,
                              hipStream_t stream) {
  (void)in_sizes; (void)n_in; (void)out_size; (void)ws_size;
  const int*   ei  = (const int*)d_in[0];
  const float* x0  = (const float*)d_in[1];
  const float* ea  = (const float*)d_in[2];
  const float* Wq  = (const float*)d_in[3];  const float* bq = (const float*)d_in[4];
  const float* Wk  = (const float*)d_in[5];  const float* bk = (const float*)d_in[6];
  const float* Wv  = (const float*)d_in[7];  const float* bv = (const float*)d_in[8];
  const float* We  = (const float*)d_in[9];  const float* be = (const float*)d_in[10];
  const float* Wsk = (const float*)d_in[11]; const float* bsk = (const float*)d_in[12];
  const float* W1  = (const float*)d_in[13]; const float* b1 = (const float*)d_in[14];
  const float* W2  = (const float*)d_in[15]; const float* b2 = (const float*)d_in[16];
  const float* g1  = (const float*)d_in[17]; const float* lb1 = (const float*)d_in[18];
  const float* g2  = (const float*)d_in[19]; const float* lb2 = (const float*)d_in[20];

  char* ws = (char*)d_ws;
  f16*   Qn     = (f16*)(ws + 0);              // 12.8M
  f16*   Kn     = (f16*)(ws + 12800000L);      // 12.8M
  f16*   Vn     = (f16*)(ws + 25600000L);      // 12.8M
  float* Skip   = (float*)(ws + 38400000L);    // 25.6M -> 64000000
  int*   offs   = (int*)(ws + 64000000L);      // 200,192
  f16*   WhAll  = (f16*)(ws + 64200192L);      // 229,376 (overlays cursor, dead after CSR)
  int*   cursor = (int*)(ws + 64200192L);
  int*   counts = (int*)(ws + 64429568L);      // 200,000
  int*   elist  = (int*)(ws + 64629760L);      // 3.2M
  int*   srcs   = (int*)(ws + 67829760L);      // 3.2M
  int*   dsts   = (int*)(ws + 71029760L);      // 3.2M
  float* den    = (float*)(ws + 74229760L);    // 1.6M
  float* node1  = (float*)(ws + 75829760L);    // 25.6M -> 101,429,760
  float* hid    = (float*)(ws + 38400000L);    // reuse Skip (dead after post_ln_div)
  float* h2     = (float*)(ws + 0);            // reuse Qn/Kn (dead after edge_attn)
  float* attn   = (float*)d_out;               // atomic accumulation target; overwritten at end

  (void)hipMemsetAsync(counts, 0, N_NODES * sizeof(int), stream);
  (void)hipMemsetAsync(attn, 0, (size_t)N_NODES * DIM * sizeof(float), stream);
  (void)hipMemsetAsync(den, 0, (size_t)N_NODES * 8 * sizeof(float), stream);
  hist_k<<<1024, 256, 0, stream>>>(ei, counts);
  scan_k<<<1, 1024, 0, stream>>>(counts, offs, cursor);
  scatter_k<<<1024, 256, 0, stream>>>(ei, cursor, elist, srcs, dsts);
  convert7<<<112, 1024, 0, stream>>>(Wq, Wk, Wv, Wsk, We, W1, W2, WhAll);

  node4_v4<<<NODE_TILES, 256, 0, stream>>>(x0, WhAll, bq, bk, bv, bsk, Qn, Kn, Vn, Skip);
  edge_attn<<<EDGE_TILES, 256, 0, stream>>>(ea, elist, srcs, dsts, WhAll + 4 * 16384, be,
                                            Qn, Kn, Vn, attn, den);
  post_ln_div<<<12500, 256, 0, stream>>>(attn, den, Skip, x0, g1, lb1, node1);
  gemm_v4<0, 1><<<NODE_TILES, 256, 0, stream>>>(node1, (long)N_NODES, NODE_TILES,
                                                WhAll + 5 * 16384, b1, hid);
  gemm_v4<0, 0><<<NODE_TILES, 256, 0, stream>>>(hid, (long)N_NODES, NODE_TILES,
                                                WhAll + 6 * 16384, b2, h2);
  post_ln<<<12500, 256, 0, stream>>>(h2, node1, g2, lb2, (float*)d_out);
}